// Round 15
// baseline (52.462 us; speedup 1.0000x reference)
//
#include <hip/hip_runtime.h>
#include <hip/hip_bf16.h>
#include <math.h>

// out[i,j] = max( (x[i]·W[j]) / (|x_i| |W_j|), 1e-10 ) + b[j]
// B=65536, IN=OUT=256, fp32 in/out.
// Round 15: window-split wave PAIRS. 1024 thr, 16 waves = 8 pairs x 2 members.
// Pair p owns rows p*32..p*32+31 (x in regs for BOTH members, 2 M-tiles);
// member m computes 8 of the 16 col-windows. Each ds_read_b128 W-frag feeds
// 2 MFMAs -> per-CU LDS read traffic 2MB -> 1MB (the dominant non-HBM cost)
// at UNCHANGED 4 waves/SIMD occupancy (R10 got the sharing but only 2/SIMD).
// x re-read by the pair member hits L2 (same block, ~us apart): FETCH watched.
// Else identical to R14: x-first burst, waves0-7 low-conflict W prologue,
// single barrier, n-outer streamed stores, no scheduling fences.

using bf16x8 = __attribute__((ext_vector_type(8))) short;   // 8 bf16 = 4 VGPRs
using f32x4  = __attribute__((ext_vector_type(4))) float;

#define W_LDS_BYTES 131072                        // 256 rows * 512 B (bf16, swizzled)
#define LDS_BYTES   (W_LDS_BYTES + 1024 + 1024)   // + winv[256] + b[256]
#define EPS 1e-10f

__device__ __forceinline__ short f2bf(float f) {
    __bf16 h = (__bf16)f;                         // RNE; pairs fuse to v_cvt_pk_bf16_f32
    return __builtin_bit_cast(short, h);
}

__global__ __launch_bounds__(1024, 4) void ffn_cosnorm_kernel(
    const float* __restrict__ x, const float* __restrict__ W,
    const float* __restrict__ b, float* __restrict__ out)
{
    extern __shared__ char smem[];
    float* winv = (float*)(smem + W_LDS_BYTES);           // [256] 1/|W_j|
    float* blds = (float*)(smem + W_LDS_BYTES + 1024);    // [256] bias

    const int t    = threadIdx.x;
    const int lane = t & 63;
    const int wave = t >> 6;                  // 0..15
    const int p    = wave & 7;                // row-pair id (rows p*32..p*32+31)
    const int m    = wave >> 3;               // window-half member (0: n<8, 1: n>=8)
    const int r16  = lane & 15;               // x row within M-tile (= D col, in-lane)
    const int kg   = lane >> 4;               // 0..3 : K-slice of 8
    const int rxor = (r16 & 7) << 4;          // W-frag read swizzle
    const size_t rowb = (size_t)blockIdx.x * 256 + (size_t)p * 32;

    const float* xp0 = x + (rowb + r16) * 256 + kg * 8;   // M-tile 0 row
    const float* xp1 = xp0 + 16 * 256;                     // M-tile 1 row

    // ---- x burst FIRST (x-first program order = the traffic optimum) ----
    float4 f0a[8], f0b[8], f1a[8], f1b[8];
    #pragma unroll
    for (int s = 0; s < 8; ++s) {
        f0a[s] = *(const float4*)(xp0 + s * 32);
        f0b[s] = *(const float4*)(xp0 + s * 32 + 4);
        f1a[s] = *(const float4*)(xp1 + s * 32);
        f1b[s] = *(const float4*)(xp1 + s * 32 + 4);
    }

    // ---- W prologue: waves 0-7 only, 2 threads/row (low-conflict R6 layout) ----
    if (wave < 8) {
        const int wrow = t >> 1;              // 0..255 (W row = output col j)
        const int half = t & 1;               // which 128-col half
        const float* wr = W + (size_t)wrow * 256 + half * 128;
        const int rx = (wrow & 7) << 4;       // swizzle term
        float ss = 0.f;
        #pragma unroll
        for (int i = 0; i < 16; ++i) {        // 16 groups of 8 floats
            float4 a = *(const float4*)(wr + i * 8);
            float4 c = *(const float4*)(wr + i * 8 + 4);
            ss = fmaf(a.x, a.x, ss); ss = fmaf(a.y, a.y, ss);
            ss = fmaf(a.z, a.z, ss); ss = fmaf(a.w, a.w, ss);
            ss = fmaf(c.x, c.x, ss); ss = fmaf(c.y, c.y, ss);
            ss = fmaf(c.z, c.z, ss); ss = fmaf(c.w, c.w, ss);
            bf16x8 v;
            v[0] = f2bf(a.x); v[1] = f2bf(a.y); v[2] = f2bf(a.z); v[3] = f2bf(a.w);
            v[4] = f2bf(c.x); v[5] = f2bf(c.y); v[6] = f2bf(c.z); v[7] = f2bf(c.w);
            const int off = wrow * 512 + ((half * 256 + i * 16) ^ rx);
            *(bf16x8*)(smem + off) = v;       // ds_write_b128
        }
        ss += __shfl_xor(ss, 1);              // combine the two halves
        if (!half) winv[wrow] = 1.0f / sqrtf(ss);
        if (t < 256) blds[t] = b[t];
    }

    // ---- convert x -> bf16 fragments + fp32 sum-of-squares (both tiles) ----
    bf16x8 xb0[8], xb1[8];                    // 64 VGPR persistent
    float ss0 = 0.f, ss1 = 0.f;
    #pragma unroll
    for (int s = 0; s < 8; ++s) {
        float4 a = f0a[s], c = f0b[s];
        bf16x8 v;
        v[0] = f2bf(a.x); v[1] = f2bf(a.y); v[2] = f2bf(a.z); v[3] = f2bf(a.w);
        v[4] = f2bf(c.x); v[5] = f2bf(c.y); v[6] = f2bf(c.z); v[7] = f2bf(c.w);
        xb0[s] = v;
        ss0 = fmaf(a.x, a.x, ss0); ss0 = fmaf(a.y, a.y, ss0);
        ss0 = fmaf(a.z, a.z, ss0); ss0 = fmaf(a.w, a.w, ss0);
        ss0 = fmaf(c.x, c.x, ss0); ss0 = fmaf(c.y, c.y, ss0);
        ss0 = fmaf(c.z, c.z, ss0); ss0 = fmaf(c.w, c.w, ss0);
        float4 a1 = f1a[s], c1 = f1b[s];
        bf16x8 w1;
        w1[0] = f2bf(a1.x); w1[1] = f2bf(a1.y); w1[2] = f2bf(a1.z); w1[3] = f2bf(a1.w);
        w1[4] = f2bf(c1.x); w1[5] = f2bf(c1.y); w1[6] = f2bf(c1.z); w1[7] = f2bf(c1.w);
        xb1[s] = w1;
        ss1 = fmaf(a1.x, a1.x, ss1); ss1 = fmaf(a1.y, a1.y, ss1);
        ss1 = fmaf(a1.z, a1.z, ss1); ss1 = fmaf(a1.w, a1.w, ss1);
        ss1 = fmaf(c1.x, c1.x, ss1); ss1 = fmaf(c1.y, c1.y, ss1);
        ss1 = fmaf(c1.w, c1.w, ss1); ss1 = fmaf(c1.z, c1.z, ss1);
    }

    // ---- x_len: butterfly over K-groups; in-lane results ----
    ss0 += __shfl_xor(ss0, 16); ss0 += __shfl_xor(ss0, 32);
    ss1 += __shfl_xor(ss1, 16); ss1 += __shfl_xor(ss1, 32);
    const float inv0 = 1.0f / sqrtf(ss0);     // 1/|x_row(r16)|
    const float inv1 = 1.0f / sqrtf(ss1);     // 1/|x_row(r16+16)|

    __syncthreads();                          // W staged; only barrier in the kernel

    // ---- n-outer over THIS member's 8 windows; each ds_read feeds 2 MFMAs ----
    const int jb = kg * 4;
    float* op0 = out + (rowb + r16) * 256;
    float* op1 = op0 + (size_t)16 * 256;

    #pragma unroll
    for (int i = 0; i < 8; ++i) {
        const int n = m * 8 + ((p + i) & 7);  // rotation by p spreads columns
        f32x4 acc0 = f32x4{0.f, 0.f, 0.f, 0.f};
        f32x4 acc1 = f32x4{0.f, 0.f, 0.f, 0.f};
        #pragma unroll
        for (int k0 = 0; k0 < 8; ++k0) {
            const int addr = (n * 16 + r16) * 512 + ((k0 * 64 + kg * 16) ^ rxor);
            bf16x8 wfr = *(const bf16x8*)(smem + addr);   // ds_read_b128 -> 2 MFMAs
            acc0 = __builtin_amdgcn_mfma_f32_16x16x32_bf16(wfr, xb0[k0], acc0, 0, 0, 0);
            acc1 = __builtin_amdgcn_mfma_f32_16x16x32_bf16(wfr, xb1[k0], acc1, 0, 0, 0);
        }
        float4 wv = *(const float4*)(winv + n * 16 + jb);
        float4 bv = *(const float4*)(blds + n * 16 + jb);
        f32x4 o0, o1;
        o0[0] = fmaxf(acc0[0] * (inv0 * wv.x), EPS) + bv.x;
        o0[1] = fmaxf(acc0[1] * (inv0 * wv.y), EPS) + bv.y;
        o0[2] = fmaxf(acc0[2] * (inv0 * wv.z), EPS) + bv.z;
        o0[3] = fmaxf(acc0[3] * (inv0 * wv.w), EPS) + bv.w;
        o1[0] = fmaxf(acc1[0] * (inv1 * wv.x), EPS) + bv.x;
        o1[1] = fmaxf(acc1[1] * (inv1 * wv.y), EPS) + bv.y;
        o1[2] = fmaxf(acc1[2] * (inv1 * wv.z), EPS) + bv.z;
        o1[3] = fmaxf(acc1[3] * (inv1 * wv.w), EPS) + bv.w;
        *(f32x4*)(op0 + n * 16 + jb) = o0;    // stores stream through compute
        *(f32x4*)(op1 + n * 16 + jb) = o1;
    }
}

extern "C" void kernel_launch(void* const* d_in, const int* in_sizes, int n_in,
                              void* d_out, int out_size, void* d_ws, size_t ws_size,
                              hipStream_t stream) {
    const float* x = (const float*)d_in[0];
    const float* W = (const float*)d_in[1];
    const float* b = (const float*)d_in[2];
    float* out = (float*)d_out;

    hipFuncSetAttribute((const void*)ffn_cosnorm_kernel,
                        hipFuncAttributeMaxDynamicSharedMemorySize, LDS_BYTES);
    ffn_cosnorm_kernel<<<dim3(256), dim3(1024), LDS_BYTES, stream>>>(x, W, b, out);
}

// Round 16
// 50.469 us; speedup vs baseline: 1.0395x; 1.0395x over previous
//
#include <hip/hip_runtime.h>
#include <hip/hip_bf16.h>
#include <math.h>

// out[i,j] = max( (x[i]·W[j]) / (|x_i| |W_j|), 1e-10 ) + b[j]
// B=65536, IN=OUT=256, fp32 in/out.
// Round 16: operand inversion + slab pipeline.
//   W in REGISTERS: wave w holds A-frags of windows {w, w+8} (64 VGPR),
//     loaded once at prologue (L2-hot); winv/bias folded via shfl (16 regs).
//   x streams through LDS: 16-row slabs, double-buffered 2x8KB, staged
//     cooperatively (coalesced fp32 -> bf16 swizzled ds_write + fp32 ssq),
//     consumed by all 8 waves (each ds_read_b128 feeds 2 MFMAs -> per-CU LDS
//     read traffic HALVED to 1MB).
//   Per-slab: [issue slab i+1 loads] [compute slab i + store] [stage i+1]
//     [barrier] -> continuous fine-grained HBM demand (fillBuffer-like),
//     no monolithic phase bursts.
//   Grid 512 x 512thr (128 rows/block), LDS ~17KB -> 2 independent blocks/CU.

using bf16x8 = __attribute__((ext_vector_type(8))) short;   // 8 bf16 = 4 VGPRs
using f32x4  = __attribute__((ext_vector_type(4))) float;

#define SLAB_BYTES 8192                    // 16 rows * 512 B (bf16, swizzled)
#define LDS_BYTES  (2 * SLAB_BYTES + 2 * 16 * 4)   // 2 slabs + ssq[2][16]
#define EPS 1e-10f

__device__ __forceinline__ short f2bf(float f) {
    __bf16 h = (__bf16)f;                  // RNE; pairs fuse to v_cvt_pk_bf16_f32
    return __builtin_bit_cast(short, h);
}

__device__ __forceinline__ float sumsq8(float4 a, float4 c, float s) {
    s = fmaf(a.x, a.x, s); s = fmaf(a.y, a.y, s);
    s = fmaf(a.z, a.z, s); s = fmaf(a.w, a.w, s);
    s = fmaf(c.x, c.x, s); s = fmaf(c.y, c.y, s);
    s = fmaf(c.z, c.z, s); s = fmaf(c.w, c.w, s);
    return s;
}

__device__ __forceinline__ bf16x8 pack8(float4 a, float4 c) {
    bf16x8 v;
    v[0] = f2bf(a.x); v[1] = f2bf(a.y); v[2] = f2bf(a.z); v[3] = f2bf(a.w);
    v[4] = f2bf(c.x); v[5] = f2bf(c.y); v[6] = f2bf(c.z); v[7] = f2bf(c.w);
    return v;
}

__global__ __launch_bounds__(512, 4) void ffn_cosnorm_kernel(
    const float* __restrict__ x, const float* __restrict__ W,
    const float* __restrict__ b, float* __restrict__ out)
{
    extern __shared__ char smem[];
    float* ssq = (float*)(smem + 2 * SLAB_BYTES);    // [2][16] per-slab row sumsq

    const int t    = threadIdx.x;
    const int lane = t & 63;
    const int wave = t >> 6;                  // 0..7
    const int r16  = lane & 15;               // slab row (= D col m, in-lane)
    const int kg   = lane >> 4;               // 0..3 : K-slice of 8
    const int rxor = (r16 & 7) << 4;          // slab read swizzle
    const size_t rowbase = (size_t)blockIdx.x * 128;

    // staging assignment: thread t stages row srow, 16B chunk c2 (8 floats)
    const int srow = t >> 5;                  // 0..15
    const int c2   = t & 31;                  // chunk within row
    const int soff = srow * 512 + ((c2 * 16) ^ ((srow & 7) << 4));
    const float* sp = x + (rowbase + srow) * 256 + c2 * 8;

    // ---- slab 0 x loads FIRST (x-first program order = traffic optimum) ----
    float4 g0 = *(const float4*)(sp);
    float4 g1 = *(const float4*)(sp + 4);

    // ---- W prologue: wave w owns windows n0=w, n1=w+8; A-frags to registers ----
    bf16x8 xw0[8], xw1[8];                    // 64 VGPR persistent
    float wv0[4], wv1[4];
    float4 bv0, bv1;
    const int n0 = wave, n1 = wave + 8;
    {
        const float* wr0 = W + (size_t)(n0 * 16 + r16) * 256 + kg * 8;
        const float* wr1 = W + (size_t)(n1 * 16 + r16) * 256 + kg * 8;
        float s0 = 0.f, s1 = 0.f;
        #pragma unroll
        for (int k0 = 0; k0 < 8; ++k0) {
            float4 a0 = *(const float4*)(wr0 + k0 * 32);
            float4 c0 = *(const float4*)(wr0 + k0 * 32 + 4);
            xw0[k0] = pack8(a0, c0);
            s0 = sumsq8(a0, c0, s0);
            float4 a1 = *(const float4*)(wr1 + k0 * 32);
            float4 c1 = *(const float4*)(wr1 + k0 * 32 + 4);
            xw1[k0] = pack8(a1, c1);
            s1 = sumsq8(a1, c1, s1);
        }
        s0 += __shfl_xor(s0, 16); s0 += __shfl_xor(s0, 32);   // full row-j sumsq
        s1 += __shfl_xor(s1, 16); s1 += __shfl_xor(s1, 32);
        const float iw0 = 1.0f / sqrtf(s0);   // 1/|W_j|, j = n*16 + (lane&15)
        const float iw1 = 1.0f / sqrtf(s1);
        #pragma unroll
        for (int r = 0; r < 4; ++r) {         // D row j' = kg*4 + r -> fold via shfl
            wv0[r] = __shfl(iw0, kg * 4 + r);
            wv1[r] = __shfl(iw1, kg * 4 + r);
        }
        bv0 = *(const float4*)(b + n0 * 16 + kg * 4);   // bias, 4 consecutive cols
        bv1 = *(const float4*)(b + n1 * 16 + kg * 4);
    }

    // ---- stage slab 0: convert, swizzled ds_write, fp32 ssq reduce ----
    {
        float sp2 = sumsq8(g0, g1, 0.f);
        *(bf16x8*)(smem + soff) = pack8(g0, g1);
        sp2 += __shfl_xor(sp2, 1);  sp2 += __shfl_xor(sp2, 2);
        sp2 += __shfl_xor(sp2, 4);  sp2 += __shfl_xor(sp2, 8);
        sp2 += __shfl_xor(sp2, 16);                  // 32 threads of this row
        if ((lane & 31) == 0) ssq[srow] = sp2;       // buffer 0
    }
    __syncthreads();

    // ---------------- slab pipeline: 8 slabs of 16 rows ----------------
    #pragma unroll
    for (int i = 0; i < 8; ++i) {
        const int cur = i & 1;
        float4 h0, h1;
        if (i < 7) {                          // issue next-slab loads (hide under compute)
            const float* np = sp + (size_t)(i + 1) * 16 * 256;
            h0 = *(const float4*)(np);
            h1 = *(const float4*)(np + 4);
        }

        // compute slab i from buf[cur]; each ds_read feeds both windows
        const float invx = 1.0f / sqrtf(ssq[cur * 16 + r16]);   // 1/|x_row|
        f32x4 a0 = f32x4{0.f, 0.f, 0.f, 0.f};
        f32x4 a1 = f32x4{0.f, 0.f, 0.f, 0.f};
        #pragma unroll
        for (int k0 = 0; k0 < 8; ++k0) {
            bf16x8 bfr = *(const bf16x8*)(smem + cur * SLAB_BYTES +
                                          r16 * 512 + ((k0 * 64 + kg * 16) ^ rxor));
            a0 = __builtin_amdgcn_mfma_f32_16x16x32_bf16(xw0[k0], bfr, a0, 0, 0, 0);
            a1 = __builtin_amdgcn_mfma_f32_16x16x32_bf16(xw1[k0], bfr, a1, 0, 0, 0);
        }
        float* op = out + (rowbase + i * 16 + r16) * 256;
        f32x4 o0, o1;
        o0[0] = fmaxf(a0[0] * (invx * wv0[0]), EPS) + bv0.x;
        o0[1] = fmaxf(a0[1] * (invx * wv0[1]), EPS) + bv0.y;
        o0[2] = fmaxf(a0[2] * (invx * wv0[2]), EPS) + bv0.z;
        o0[3] = fmaxf(a0[3] * (invx * wv0[3]), EPS) + bv0.w;
        o1[0] = fmaxf(a1[0] * (invx * wv1[0]), EPS) + bv1.x;
        o1[1] = fmaxf(a1[1] * (invx * wv1[1]), EPS) + bv1.y;
        o1[2] = fmaxf(a1[2] * (invx * wv1[2]), EPS) + bv1.z;
        o1[3] = fmaxf(a1[3] * (invx * wv1[3]), EPS) + bv1.w;
        *(f32x4*)(op + n0 * 16 + kg * 4) = o0;   // stores stream every slab
        *(f32x4*)(op + n1 * 16 + kg * 4) = o1;

        // stage slab i+1 into buf[cur^1] (its last readers finished at iter i-1)
        if (i < 7) {
            float sp2 = sumsq8(h0, h1, 0.f);
            *(bf16x8*)(smem + (cur ^ 1) * SLAB_BYTES + soff) = pack8(h0, h1);
            sp2 += __shfl_xor(sp2, 1);  sp2 += __shfl_xor(sp2, 2);
            sp2 += __shfl_xor(sp2, 4);  sp2 += __shfl_xor(sp2, 8);
            sp2 += __shfl_xor(sp2, 16);
            if ((lane & 31) == 0) ssq[(cur ^ 1) * 16 + srow] = sp2;
        }
        __syncthreads();
    }
}

extern "C" void kernel_launch(void* const* d_in, const int* in_sizes, int n_in,
                              void* d_out, int out_size, void* d_ws, size_t ws_size,
                              hipStream_t stream) {
    const float* x = (const float*)d_in[0];
    const float* W = (const float*)d_in[1];
    const float* b = (const float*)d_in[2];
    float* out = (float*)d_out;

    hipFuncSetAttribute((const void*)ffn_cosnorm_kernel,
                        hipFuncAttributeMaxDynamicSharedMemorySize, LDS_BYTES);
    ffn_cosnorm_kernel<<<dim3(512), dim3(512), LDS_BYTES, stream>>>(x, W, b, out);
}

// Round 17
// 35.648 us; speedup vs baseline: 1.4717x; 1.4158x over previous
//
#include <hip/hip_runtime.h>
#include <hip/hip_bf16.h>
#include <math.h>

// out[i,j] = max( (x[i]·W[j]) / (|x_i| |W_j|), 1e-10 ) + b[j]
// B=65536, IN=OUT=256, fp32 in/out.
// Round 17: R14 with the x drain converted to global_load_lds DMA.
// Mechanism: VGPR-destined loads are capped at ~4 in flight/wave by the
// allocator (R7/R8/R11/R12 evidence) -> 4KB/CU outstanding -> 2.7 TB/s
// Little's-law wall (= every round's observed plateau). global_load_lds
// needs no dest regs: 8 x 1KB DMA per wave issued up-front = 128KB/CU
// outstanding -> x drains BW-bound. x stages through the W-LDS region
// (wave-private 2x4KB ping-pong, zero barriers) BEFORE W is staged there.
// Then: barrier, W staging (R11 layout), barrier, R14 n-outer loop verbatim.

using bf16x8 = __attribute__((ext_vector_type(8))) short;   // 8 bf16 = 4 VGPRs
using f32x4  = __attribute__((ext_vector_type(4))) float;

#define W_LDS_BYTES 131072                        // 256 rows * 512 B (bf16, swizzled)
#define LDS_BYTES   (W_LDS_BYTES + 1024 + 1024)   // + winv[256] + b[256]
#define EPS 1e-10f

__device__ __forceinline__ short f2bf(float f) {
    __bf16 h = (__bf16)f;                         // RNE; pairs fuse to v_cvt_pk_bf16_f32
    return __builtin_bit_cast(short, h);
}

__device__ __forceinline__ void dma16(const float* g, char* l) {
    __builtin_amdgcn_global_load_lds(
        (const __attribute__((address_space(1))) void*)g,
        (__attribute__((address_space(3))) void*)l,
        16 /*bytes per lane*/, 0, 0);
}

__global__ __launch_bounds__(1024, 4) void ffn_cosnorm_kernel(
    const float* __restrict__ x, const float* __restrict__ W,
    const float* __restrict__ b, float* __restrict__ out)
{
    extern __shared__ char smem[];
    float* winv = (float*)(smem + W_LDS_BYTES);           // [256] 1/|W_j|
    float* blds = (float*)(smem + W_LDS_BYTES + 1024);    // [256] bias

    const int t    = threadIdx.x;
    const int lane = t & 63;
    const int wave = t >> 6;                  // 0..15
    const int r16  = lane & 15;               // x row within M-tile (= D col, in-lane)
    const int kg   = lane >> 4;               // 0..3 : K-slice of 8
    const int rxor = (r16 & 7) << 4;          // W-frag read swizzle
    const size_t rowb = (size_t)blockIdx.x * 256 + (size_t)wave * 16;

    // wave-private staging slab: 2 quarter-buffers of 4KB (16 rows x 256B)
    char* slab = smem + wave * 8192;

    // DMA lane mapping: instr j covers wave-local rows 4j..4j+3; lane l ->
    // row16 = 4j + (l>>4), 16B chunk c = l&15. Global source pre-swizzled so
    // the ds_read side can use a conflict-reducing XOR (m173 pattern).
    const int drow = lane >> 4;               // row within the 4-row group
    const int dc   = lane & 15;               // 16B chunk 0..15

    // ---- x DMA burst FIRST: 8 x global_load_lds (q0->buf0, q1->buf1) ----
    #pragma unroll
    for (int q = 0; q < 2; ++q) {
        #pragma unroll
        for (int j = 0; j < 4; ++j) {
            const int row16 = j * 4 + drow;
            const float* g = x + (rowb + row16) * 256 + q * 64
                               + ((dc ^ (row16 & 7)) << 2);
            dma16(g, slab + (q & 1) * 4096 + j * 1024);
        }
    }

    // ---- convert quarters as they land; refill freed buffers with q2,q3 ----
    bf16x8 xb[8];                             // 32 VGPR persistent
    float ssx = 0.f;
    #pragma unroll
    for (int q = 0; q < 4; ++q) {
        // wait for quarter q: q<3 -> 4 younger DMA ops may remain in flight
        if (q < 3) asm volatile("s_waitcnt vmcnt(4)" ::: "memory");
        else       asm volatile("s_waitcnt vmcnt(0)" ::: "memory");
        __builtin_amdgcn_sched_barrier(0);
        // lane (r16,kg) reads its row's 8 floats for k0=0,1 of this quarter
        #pragma unroll
        for (int k0 = 0; k0 < 2; ++k0) {
            const int ch0 = (k0 * 8 + kg * 2) ^ (r16 & 7);
            const int ch1 = (k0 * 8 + kg * 2 + 1) ^ (r16 & 7);
            f32x4 a = *(const f32x4*)(slab + (q & 1) * 4096 + r16 * 256 + ch0 * 16);
            f32x4 c = *(const f32x4*)(slab + (q & 1) * 4096 + r16 * 256 + ch1 * 16);
            bf16x8 v;
            v[0] = f2bf(a[0]); v[1] = f2bf(a[1]); v[2] = f2bf(a[2]); v[3] = f2bf(a[3]);
            v[4] = f2bf(c[0]); v[5] = f2bf(c[1]); v[6] = f2bf(c[2]); v[7] = f2bf(c[3]);
            xb[q * 2 + k0] = v;
            ssx = fmaf(a[0], a[0], ssx); ssx = fmaf(a[1], a[1], ssx);
            ssx = fmaf(a[2], a[2], ssx); ssx = fmaf(a[3], a[3], ssx);
            ssx = fmaf(c[0], c[0], ssx); ssx = fmaf(c[1], c[1], ssx);
            ssx = fmaf(c[2], c[2], ssx); ssx = fmaf(c[3], c[3], ssx);
        }
        if (q < 2) {                          // refill this buffer with quarter q+2
            asm volatile("s_waitcnt lgkmcnt(0)" ::: "memory");   // reads done
            __builtin_amdgcn_sched_barrier(0);
            const int nq = q + 2;
            #pragma unroll
            for (int j = 0; j < 4; ++j) {
                const int row16 = j * 4 + drow;
                const float* g = x + (rowb + row16) * 256 + nq * 64
                                   + ((dc ^ (row16 & 7)) << 2);
                dma16(g, slab + (nq & 1) * 4096 + j * 1024);
            }
        }
    }

    // ---- x_len: butterfly over K-groups; in-lane result ----
    ssx += __shfl_xor(ssx, 16); ssx += __shfl_xor(ssx, 32);
    const float inv = 1.0f / sqrtf(ssx);      // 1/|x_row(r16)|

    __syncthreads();                          // all waves done with slab region

    // ---- W staging into the same region (R11 layout: 4 threads/row) ----
    {
        const int wrow = t >> 2;              // 0..255 W row (output col j)
        const int q    = t & 3;               // 64-float quarter of the row
        const float* wr = W + (size_t)wrow * 256 + q * 64;
        const int rx = (wrow & 7) << 4;       // swizzle term
        float ss = 0.f;
        #pragma unroll
        for (int i = 0; i < 8; ++i) {         // 8 groups of 8 floats
            float4 a = *(const float4*)(wr + i * 8);
            float4 c = *(const float4*)(wr + i * 8 + 4);
            ss = fmaf(a.x, a.x, ss); ss = fmaf(a.y, a.y, ss);
            ss = fmaf(a.z, a.z, ss); ss = fmaf(a.w, a.w, ss);
            ss = fmaf(c.x, c.x, ss); ss = fmaf(c.y, c.y, ss);
            ss = fmaf(c.z, c.z, ss); ss = fmaf(c.w, c.w, ss);
            bf16x8 v;
            v[0] = f2bf(a.x); v[1] = f2bf(a.y); v[2] = f2bf(a.z); v[3] = f2bf(a.w);
            v[4] = f2bf(c.x); v[5] = f2bf(c.y); v[6] = f2bf(c.z); v[7] = f2bf(c.w);
            const int off = wrow * 512 + ((q * 128 + i * 16) ^ rx);
            *(bf16x8*)(smem + off) = v;       // ds_write_b128
        }
        ss += __shfl_xor(ss, 1);              // combine the 4 quarters
        ss += __shfl_xor(ss, 2);
        if (q == 0) winv[wrow] = 1.0f / sqrtf(ss);
        if (q == 1) blds[wrow] = b[wrow];
    }
    __syncthreads();                          // W staged

    // ---------------- n-outer loop (R14 verbatim): compute, store, repeat ----
    const int jb = kg * 4;
    float* op = out + (rowb + r16) * 256;

    #pragma unroll
    for (int n = 0; n < 16; ++n) {
        f32x4 acc = f32x4{0.f, 0.f, 0.f, 0.f};
        #pragma unroll
        for (int k0 = 0; k0 < 8; ++k0) {
            const int addr = (n * 16 + r16) * 512 + ((k0 * 64 + kg * 16) ^ rxor);
            bf16x8 wfr = *(const bf16x8*)(smem + addr);   // ds_read_b128
            acc = __builtin_amdgcn_mfma_f32_16x16x32_bf16(wfr, xb[k0], acc, 0, 0, 0);
        }
        float4 wv = *(const float4*)(winv + n * 16 + jb);
        float4 bv = *(const float4*)(blds + n * 16 + jb);
        f32x4 o;
        o[0] = fmaxf(acc[0] * (inv * wv.x), EPS) + bv.x;
        o[1] = fmaxf(acc[1] * (inv * wv.y), EPS) + bv.y;
        o[2] = fmaxf(acc[2] * (inv * wv.z), EPS) + bv.z;
        o[3] = fmaxf(acc[3] * (inv * wv.w), EPS) + bv.w;
        *(f32x4*)(op + n * 16 + jb) = o;      // stores stream through compute
    }
}

extern "C" void kernel_launch(void* const* d_in, const int* in_sizes, int n_in,
                              void* d_out, int out_size, void* d_ws, size_t ws_size,
                              hipStream_t stream) {
    const float* x = (const float*)d_in[0];
    const float* W = (const float*)d_in[1];
    const float* b = (const float*)d_in[2];
    float* out = (float*)d_out;

    hipFuncSetAttribute((const void*)ffn_cosnorm_kernel,
                        hipFuncAttributeMaxDynamicSharedMemorySize, LDS_BYTES);
    ffn_cosnorm_kernel<<<dim3(256), dim3(1024), LDS_BYTES, stream>>>(x, W, b, out);
}